// Round 13
// baseline (180.996 us; speedup 1.0000x reference)
//
#include <hip/hip_runtime.h>
#include <hip/hip_fp16.h>

#define CN0 200000
#define CN1 100000
#define CN2 50000
#define CM 16
#define CVL 32
#define CK 32
#define CD 64
#define CEPS 1e-12f

typedef _Float16 half2_t __attribute__((ext_vector_type(2)));
typedef short bf16x8 __attribute__((ext_vector_type(8)));
typedef float f32x4 __attribute__((ext_vector_type(4)));

union H4 { __half2 h2[2]; uint2 u; };

__device__ __forceinline__ uint f32_to_bf16(float f) {
    uint u = __builtin_bit_cast(uint, f);
    return (u + 0x7fffu + ((u >> 16) & 1u)) >> 16;   // RNE
}

__device__ __forceinline__ uint pk_add(uint a, uint b) {
    return __builtin_bit_cast(uint, __builtin_bit_cast(half2_t, a) +
                                    __builtin_bit_cast(half2_t, b));
}
__device__ __forceinline__ uint4 pk_add4(uint4 a, uint4 b) {
    uint4 r;
    r.x = pk_add(a.x, b.x); r.y = pk_add(a.y, b.y);
    r.z = pk_add(a.z, b.z); r.w = pk_add(a.w, b.w);
    return r;
}

// Stage 0: ft_lv0[n] = concat(sum_m x, 0.5*(s^2 - sum x^2)), fp16 out.
// 8 threads/node; at HBM floor (~73 us).
__global__ void k_lv0(const float* __restrict__ x, __half* __restrict__ ft0) {
    int t = blockIdx.x * blockDim.x + threadIdx.x;
    int n = t >> 3;
    int q = t & 7;
    if (n >= CN0) return;
    const float4* xp = reinterpret_cast<const float4*>(x + (size_t)n * (CM * CVL)) + q;
    float4 s = make_float4(0.f, 0.f, 0.f, 0.f);
    float4 sq = make_float4(0.f, 0.f, 0.f, 0.f);
#pragma unroll
    for (int m = 0; m < CM; ++m) {
        float4 v = xp[m * (CVL / 4)];
        s.x += v.x; s.y += v.y; s.z += v.z; s.w += v.w;
        sq.x += v.x * v.x; sq.y += v.y * v.y; sq.z += v.z * v.z; sq.w += v.w * v.w;
    }
    float4 cr;
    cr.x = 0.5f * (s.x * s.x - sq.x);
    cr.y = 0.5f * (s.y * s.y - sq.y);
    cr.z = 0.5f * (s.z * s.z - sq.z);
    cr.w = 0.5f * (s.w * s.w - sq.w);
    uint2* orow = reinterpret_cast<uint2*>(ft0 + (size_t)n * CD);
    H4 pa, pb;
    pa.h2[0] = __floats2half2_rn(s.x, s.y);
    pa.h2[1] = __floats2half2_rn(s.z, s.w);
    pb.h2[0] = __floats2half2_rn(cr.x, cr.y);
    pb.h2[1] = __floats2half2_rn(cr.z, cr.w);
    orow[q] = pa.u;
    orow[8 + q] = pb.u;
}

// One-time W -> bf16 B-fragment transpose for mfma_f32_16x16x32_bf16.
__global__ void k_prepw(const float* __restrict__ W1, const float* __restrict__ W2,
                        ushort* __restrict__ Wf1, ushort* __restrict__ Wf2) {
    const float* W = blockIdx.x ? W2 : W1;
    ushort* Wf = blockIdx.x ? Wf2 : Wf1;
    for (int e = threadIdx.x; e < 1024; e += blockDim.x) {
        const int f = e >> 6, l = e & 63;
        const int t = f >> 2, c = f & 3;
        const int n = (t << 4) + (l & 15);
        const int k0 = (c << 5) + ((l >> 4) << 3);
        uint w[8];
#pragma unroll
        for (int j = 0; j < 8; ++j) w[j] = f32_to_bf16(W[(k0 + j) * CD + n]);
        uint4 v;
        v.x = w[0] | (w[1] << 16); v.y = w[2] | (w[3] << 16);
        v.z = w[4] | (w[5] << 16); v.w = w[6] | (w[7] << 16);
        reinterpret_cast<uint4*>(Wf)[e] = v;
    }
}

// Conv via MFMA, wide-gather variant: wave owns 16 nodes. lane -> (g=lane>>3:
// 4 neighbors g,8+g,16+g,24+g; h=lane&7: dim-octet 8h..8h+7 = one 16B block).
// 5 VMEM/node (4 neighbor uint4 + self uint4, was 9x uint2). fp16 pk-add tree
// to 4-way in-lane, packed shfl_xor(8) -> 8-way (bounded, proven r11), then
// f32 shfl_xor(16/32). A-tile store: one ds_write_b128 from g<2 lanes at
// gran j=(g&1)*8+h with the same XOR swizzle as r10-12. adj rows via per-wave
// LDS tile; ids via s_loads; B-fragments from global (L1/L2-hot); no barrier.
template<bool NORM, typename OutT>
__global__ void __launch_bounds__(256)
k_conv(const __half* __restrict__ ftin, const int* __restrict__ ids,
       const int* __restrict__ adj, const ushort* __restrict__ Wf,
       const float* __restrict__ bias, OutT* __restrict__ ftout, int nNodes)
{
    __shared__ char Albs[4 * 4096];   // per-wave 16x128 bf16 A-tile, swizzled
    __shared__ int adjT[4 * 512];     // per-wave 16x32 adjacency tile (8 KiB)

    const int lane = threadIdx.x & 63;
    const int wv = __builtin_amdgcn_readfirstlane(threadIdx.x >> 6);
    const int g = lane >> 3;   // neighbor-group 0..7
    const int h = lane & 7;    // dim-octet (dims 8h..8h+7)
    char* Aw = Albs + (wv << 12);
    int* adjW = adjT + (wv << 9);
    // write-side: lanes g<2 store gran j (16B k-octet): g=0 -> c0 octet h,
    // g=1 -> c1 octet 8+h.  byte = (j<<4) ^ ((p&7)<<4)
    const int jgran = ((g & 1) << 3) + h;
    // read-side (MFMA A-frag): row m = lane&15, k-group lp = lane>>4
    const int mrow = lane & 15;
    const int lp = lane >> 4;
    const int mm7 = mrow & 7;
    const float bb0 = bias[mrow], bb1 = bias[16 + mrow];
    const float bb2 = bias[32 + mrow], bb3 = bias[48 + mrow];
    const uint4* Bg = reinterpret_cast<const uint4*>(Wf);

    const int nB = (nNodes + 63) >> 6;
    for (int b = blockIdx.x; b < nB; b += gridDim.x) {
        const int base = __builtin_amdgcn_readfirstlane((b << 6) + (wv << 4));
        const int cbase = __builtin_amdgcn_readfirstlane(
            base < nNodes - 16 ? base : nNodes - 16);   // dup work for tail waves
        // ---- pass prologue: ids (scalar) + adj tile (vector -> LDS) ----
        int idv[16];
#pragma unroll
        for (int p = 0; p < 16; ++p) idv[p] = ids[cbase + p];   // s_loads
        {
            const uint4* src = reinterpret_cast<const uint4*>(adj + ((size_t)cbase << 5));
            uint4* dst = reinterpret_cast<uint4*>(adjW);
            dst[lane] = src[lane];
            dst[64 + lane] = src[64 + lane];
        }
        // ---- gather + A-tile staging, 16 nodes, 4-deep pipelined ----
#pragma unroll 4
        for (int p = 0; p < 16; ++p) {
            const int* arow = adjW + (p << 5);
            const int r0 = arow[g], r1 = arow[8 + g];
            const int r2 = arow[16 + g], r3 = arow[24 + g];
            const uint4 sv = *reinterpret_cast<const uint4*>(
                ftin + ((size_t)idv[p] << 6) + (h << 3));
            auto FL = [&](int r) -> uint4 {
                return *reinterpret_cast<const uint4*>(
                    ftin + ((size_t)r << 6) + (h << 3));
            };
            const uint4 f0 = FL(r0), f1 = FL(r1), f2 = FL(r2), f3 = FL(r3);
            const uint4 a01 = pk_add4(f0, f1);
            const uint4 a23 = pk_add4(f2, f3);
            uint4 t4 = pk_add4(a01, a23);          // 4-way fp16 sums
            uint4 sh;                               // packed cross-group xor 8
            sh.x = __shfl_xor(t4.x, 8); sh.y = __shfl_xor(t4.y, 8);
            sh.z = __shfl_xor(t4.z, 8); sh.w = __shfl_xor(t4.w, 8);
            t4 = pk_add4(t4, sh);                   // 8-way fp16 sums (safe)
            const half2_t t0 = __builtin_bit_cast(half2_t, t4.x);
            const half2_t t1 = __builtin_bit_cast(half2_t, t4.y);
            const half2_t t2 = __builtin_bit_cast(half2_t, t4.z);
            const half2_t t3 = __builtin_bit_cast(half2_t, t4.w);
            float pl[8] = {(float)t0.x, (float)t0.y, (float)t1.x, (float)t1.y,
                           (float)t2.x, (float)t2.y, (float)t3.x, (float)t3.y};
#pragma unroll
            for (int d = 0; d < 8; ++d) {
                pl[d] += __shfl_xor(pl[d], 16);
                pl[d] += __shfl_xor(pl[d], 32);
            }
            const half2_t s0 = __builtin_bit_cast(half2_t, sv.x);
            const half2_t s1 = __builtin_bit_cast(half2_t, sv.y);
            const half2_t s2 = __builtin_bit_cast(half2_t, sv.z);
            const half2_t s3 = __builtin_bit_cast(half2_t, sv.w);
            const float sl[8] = {(float)s0.x, (float)s0.y, (float)s1.x, (float)s1.y,
                                 (float)s2.x, (float)s2.y, (float)s3.x, (float)s3.y};
            const bool mul = (g & 1);               // odd groups: "*" rows
            float w[8];
#pragma unroll
            for (int d = 0; d < 8; ++d) w[d] = mul ? sl[d] * pl[d] : sl[d] + pl[d];
            uint pk0, pk1, pk2, pk3;
            asm("v_cvt_pk_bf16_f32 %0, %1, %2" : "=v"(pk0) : "v"(w[0]), "v"(w[1]));
            asm("v_cvt_pk_bf16_f32 %0, %1, %2" : "=v"(pk1) : "v"(w[2]), "v"(w[3]));
            asm("v_cvt_pk_bf16_f32 %0, %1, %2" : "=v"(pk2) : "v"(w[4]), "v"(w[5]));
            asm("v_cvt_pk_bf16_f32 %0, %1, %2" : "=v"(pk3) : "v"(w[6]), "v"(w[7]));
            if (g < 2) {
                uint4 wq; wq.x = pk0; wq.y = pk1; wq.z = pk2; wq.w = pk3;
                *reinterpret_cast<uint4*>(
                    Aw + ((p << 8) + ((jgran << 4) ^ ((p & 7) << 4)))) = wq;
            }
        }
        // same-wave ds_write -> ds_read: lgkmcnt ordering, no barrier needed.
        // ---- MFMA: D[16 nodes][64] = A[16][128] x W[128][64] + b ----
        f32x4 acc0 = {bb0, bb0, bb0, bb0}, acc1 = {bb1, bb1, bb1, bb1};
        f32x4 acc2 = {bb2, bb2, bb2, bb2}, acc3 = {bb3, bb3, bb3, bb3};
#pragma unroll
        for (int c = 0; c < 4; ++c) {
            const int gran = ((c << 2) | lp) ^ mm7;
            const bf16x8 a = *reinterpret_cast<const bf16x8*>(
                Aw + (mrow << 8) + (gran << 4));
            acc0 = __builtin_amdgcn_mfma_f32_16x16x32_bf16(
                a, __builtin_bit_cast(bf16x8, Bg[(0 * 4 + c) * 64 + lane]), acc0, 0, 0, 0);
            acc1 = __builtin_amdgcn_mfma_f32_16x16x32_bf16(
                a, __builtin_bit_cast(bf16x8, Bg[(1 * 4 + c) * 64 + lane]), acc1, 0, 0, 0);
            acc2 = __builtin_amdgcn_mfma_f32_16x16x32_bf16(
                a, __builtin_bit_cast(bf16x8, Bg[(2 * 4 + c) * 64 + lane]), acc2, 0, 0, 0);
            acc3 = __builtin_amdgcn_mfma_f32_16x16x32_bf16(
                a, __builtin_bit_cast(bf16x8, Bg[(3 * 4 + c) * 64 + lane]), acc3, 0, 0, 0);
        }
        // ---- epilogue: relu (+ norm), store. C layout: col=lane&15,
        // node-in-tile = lp*4 + reg ----
        float z0[4], z1[4], z2[4], z3[4];
#pragma unroll
        for (int r = 0; r < 4; ++r) {
            z0[r] = fmaxf(acc0[r], 0.f);
            z1[r] = fmaxf(acc1[r], 0.f);
            z2[r] = fmaxf(acc2[r], 0.f);
            z3[r] = fmaxf(acc3[r], 0.f);
        }
        if (NORM) {
#pragma unroll
            for (int r = 0; r < 4; ++r) {
                float ss = z0[r] * z0[r] + z1[r] * z1[r] + z2[r] * z2[r] + z3[r] * z3[r];
                ss += __shfl_xor(ss, 1);
                ss += __shfl_xor(ss, 2);
                ss += __shfl_xor(ss, 4);
                ss += __shfl_xor(ss, 8);
                const float inv = 1.0f / fmaxf(sqrtf(ss), CEPS);
                z0[r] *= inv; z1[r] *= inv; z2[r] *= inv; z3[r] *= inv;
            }
        }
#pragma unroll
        for (int r = 0; r < 4; ++r) {
            const int node = base + (lp << 2) + r;
            if (node < nNodes) {
                OutT* orow = ftout + (size_t)node * CD + mrow;
                orow[0]  = (OutT)z0[r];
                orow[16] = (OutT)z1[r];
                orow[32] = (OutT)z2[r];
                orow[48] = (OutT)z3[r];
            }
        }
    }
}

extern "C" void kernel_launch(void* const* d_in, const int* in_sizes, int n_in,
                              void* d_out, int out_size, void* d_ws, size_t ws_size,
                              hipStream_t stream) {
    const float* node_feats  = (const float*)d_in[0];
    const int*   node_l1_ids = (const int*)d_in[1];
    const int*   adj1        = (const int*)d_in[2];
    const int*   node2_pos   = (const int*)d_in[3];
    const int*   adj2        = (const int*)d_in[4];
    const float* W1          = (const float*)d_in[5];
    const float* b1          = (const float*)d_in[6];
    const float* W2          = (const float*)d_in[7];
    const float* b2          = (const float*)d_in[8];
    float* out = (float*)d_out;

    __half* ft0 = (__half*)d_ws;                   // 25.6 MB
    __half* ft1 = ft0 + (size_t)CN0 * CD;          // 12.8 MB
    ushort* Wf1 = (ushort*)(ft1 + (size_t)CN1 * CD);  // 16 KB
    ushort* Wf2 = Wf1 + 8192;                          // 16 KB

    k_prepw<<<2, 256, 0, stream>>>(W1, W2, Wf1, Wf2);
    int t1 = CN0 * 8;
    k_lv0<<<(t1 + 255) / 256, 256, 0, stream>>>(node_feats, ft0);
    const int nB1 = (CN1 + 63) / 64;
    const int nB2 = (CN2 + 63) / 64;
    k_conv<false, __half><<<nB1, 256, 0, stream>>>(ft0, node_l1_ids, adj1, Wf1, b1, ft1, CN1);
    k_conv<true, float><<<nB2, 256, 0, stream>>>(ft1, node2_pos, adj2, Wf2, b2, out, CN2);
}